// Round 5
// baseline (68.985 us; speedup 1.0000x reference)
//
#include <hip/hip_runtime.h>
#include <hip/hip_bf16.h>
#include <cstdint>
#include <cstddef>

// Spatiotemporal dual-softmax attention, MI355X (gfx950).
// B=4, C=64, CI=32, N=H*W=4096. Flash-style, never materializes the 4096^2
// energy matrix. Round-5 structure: 2 launches.
//   proj  (512 blk x 512): per-frame fused BN-folded projections.
//   apply (512 blk x 1024): 16 waves, EACH wave owns all 64 m-rows (4 afrags,
//         8 PV accumulators) and a 32-col slice of each 512-col window ->
//         LDS reads amortized 4x vs r4. Swapped-operand energy MFMA -> exp2
//         (theta pre-scaled by log2e; energies provably << 80, no max
//         subtraction) -> K=16 PV MFMA from registers -> 16-way tree combine
//         in LDS -> fused output conv + BN + residual.

#define B_  4
#define C_  64
#define CI_ 32
#define N_  4096
static constexpr float EPS_   = 1e-5f;
static constexpr float LOG2E_ = 1.4426950408889634f;

typedef __attribute__((ext_vector_type(8))) short  short8;
typedef __attribute__((ext_vector_type(4))) short  short4v;
typedef __attribute__((ext_vector_type(4))) float  float4v;

__device__ __forceinline__ short f2bf(float f) {
    unsigned u = __float_as_uint(f);
    unsigned r = (u + 0x7fffu + ((u >> 16) & 1u)) >> 16;   // RNE
    return (short)r;
}

__device__ __forceinline__ float4v mfma16(short4v a, short4v b, float4v c) {
#if __has_builtin(__builtin_amdgcn_mfma_f32_16x16x16bf16_1k)
    return __builtin_amdgcn_mfma_f32_16x16x16bf16_1k(a, b, c, 0, 0, 0);
#else
    float4v d;
    asm("v_mfma_f32_16x16x16_bf16 %0, %1, %2, %3" : "=v"(d) : "v"(a), "v"(b), "v"(c));
    return d;
#endif
}

// ---------------------------------------------------------------------------
// Fused per-frame projections. side = blk>>8: 0: x1 -> {theta*log2e, g1};
// 1: x2 -> {phi, g2}. Theta/phi written [b][n][32] (energy-frag layout);
// g written [b][32][n] (V layout). 64 cols/block, 512 threads (8 o-groups).
// ---------------------------------------------------------------------------
__global__ __launch_bounds__(512) void proj_kernel(
    const float* __restrict__ x1, const float* __restrict__ x2,
    const float* __restrict__ g_w, const float* __restrict__ g_b, const float* __restrict__ g_bn,
    const float* __restrict__ t_w, const float* __restrict__ t_b, const float* __restrict__ t_bn,
    const float* __restrict__ p_w, const float* __restrict__ p_b, const float* __restrict__ p_bn,
    short* __restrict__ th_t, short* __restrict__ ph_t,
    short* __restrict__ g1l, short* __restrict__ g2l)
{
    const int side = blockIdx.x >> 8;
    const int rb   = blockIdx.x & 255;
    const int b    = rb >> 6;
    const int n0   = (rb & 63) * 64;
    const int tid  = threadIdx.x;

    const float* x   = side ? x2   : x1;
    const float* wA  = side ? p_w  : t_w;
    const float* bA  = side ? p_b  : t_b;
    const float* bnA = side ? p_bn : t_bn;
    short* outA      = side ? ph_t : th_t;
    short* outG      = side ? g2l  : g1l;
    const float scaleA = side ? 1.0f : LOG2E_;   // theta carries log2e

    __shared__ float xs[64][64];        // 16 KB
    __shared__ float wf[2][CI_][C_];    // 16 KB  [0]=A-proj, [1]=g
    __shared__ float bfold[2][CI_];

    for (int it = 0; it < 4; it++) {                 // fold both weight sets
        int idx = it * 512 + tid;                    // [o][c] flat, 2048
        int c = idx & 63;
        float invA = bnA[c]  * rsqrtf(bnA[192 + c]  + EPS_);
        float invG = g_bn[c] * rsqrtf(g_bn[192 + c] + EPS_);
        (&wf[0][0][0])[idx] = wA[idx]  * invA;
        (&wf[1][0][0])[idx] = g_w[idx] * invG;
    }
    if (tid < 2 * CI_) {
        int set = tid >> 5, o = tid & 31;
        const float* bn = set ? g_bn : bnA;
        const float* w  = set ? g_w  : wA;
        const float* bs = set ? g_b  : bA;
        float s = bs[o];
        for (int c = 0; c < C_; c++) {
            float inv = bn[c] * rsqrtf(bn[192 + c] + EPS_);
            s += w[o * C_ + c] * (bn[64 + c] - bn[128 + c] * inv);
        }
        bfold[set][o] = s;
    }
    const float* xb = x + (size_t)b * C_ * N_ + n0;
    for (int it = 0; it < 2; it++) {                 // 64c x 64n floats
        int idx = it * 512 + tid;
        int c = idx >> 4, nq = idx & 15;
        *(float4*)&xs[c][nq * 4] = *(const float4*)(xb + (size_t)c * N_ + nq * 4);
    }
    __syncthreads();

    const int n  = tid & 63;
    const int og = tid >> 6;            // channels og*4..og*4+3
    float accA[4], accG[4];
#pragma unroll
    for (int o = 0; o < 4; o++) { accA[o] = bfold[0][og * 4 + o]; accG[o] = bfold[1][og * 4 + o]; }
    for (int c = 0; c < C_; c++) {
        float xv = xs[c][n];
#pragma unroll
        for (int o = 0; o < 4; o++) {
            accA[o] += wf[0][og * 4 + o][c] * xv;
            accG[o] += wf[1][og * 4 + o][c] * xv;
        }
    }
    short4v v;
#pragma unroll
    for (int o = 0; o < 4; o++) v[o] = f2bf(accA[o] * scaleA);
    *(short4v*)(outA + ((size_t)b * N_ + n0 + n) * CI_ + og * 4) = v;
#pragma unroll
    for (int o = 0; o < 4; o++)
        outG[((size_t)b * CI_ + og * 4 + o) * N_ + n0 + n] = f2bf(accG[o]);
}

// ---------------------------------------------------------------------------
// Apply (fused softmax-sum + PV + output conv + residual).
// 16 waves; wave wv handles all 64 m-rows x cols [win*512 + wv*32, +32).
// ---------------------------------------------------------------------------
__global__ __launch_bounds__(1024, 4) void apply_kernel(
    const short* __restrict__ th, const short* __restrict__ ph,
    const short* __restrict__ g1l, const short* __restrict__ g2l,
    const float* __restrict__ x1, const float* __restrict__ x2,
    const float* __restrict__ Ww, const float* __restrict__ Wb,
    const float* __restrict__ w_bn,
    float* __restrict__ out)
{
    const int side = blockIdx.x >> 8;
    const int rb   = blockIdx.x & 255;
    const short* A  = side ? th : ph;       // rows = softmax/output dim (m)
    const short* Bm = side ? ph : th;       // cols = reduction dim (n)
    const short* V  = side ? g2l : g1l;
    const int b  = rb >> 6;
    const int r0 = (rb & 63) * 64;
    const int tid = threadIdx.x;
    const int wv = tid >> 6, lane = tid & 63;
    const int lg = lane >> 4, lr = lane & 15;

    // main loop: lbB [512][40]s = 40960 | lvV [32][520]s = 33280  -> 74240 B
    __shared__ __align__(16) char smem[74240];
    short (*lbB)[40]  = (short(*)[40])smem;
    short (*lvV)[520] = (short(*)[520])(smem + 40960);
    // epilogue overlays (all dead vs main-loop by barriers)
    float (*buf4)[64][36] = (float(*)[64][36])smem;           // 36864
    float (*sums)[64]     = (float(*)[64])(smem + 36864);     //  4096
    float *sumtot         = (float*)(smem + 40960);           //   256
    float (*wf2)[CI_]     = (float(*)[CI_])(smem + 41216);    //  8192
    float *bf2v           = (float*)(smem + 49408);           //   256

    const short* Ab = A  + (size_t)b * N_ * CI_;
    const short* Bb = Bm + (size_t)b * N_ * CI_;
    const short* Vb = V  + (size_t)b * CI_ * N_;

    short8 afrag[4];
#pragma unroll
    for (int t = 0; t < 4; t++)
        afrag[t] = *(const short8*)(Ab + (size_t)(r0 + t * 16 + lr) * CI_ + lg * 8);

    const float4v zero4 = {0.f, 0.f, 0.f, 0.f};
    float4v acc[4][2];
#pragma unroll
    for (int t = 0; t < 4; t++) { acc[t][0] = zero4; acc[t][1] = zero4; }
    float srun[4] = {0.f, 0.f, 0.f, 0.f};
    const int c0 = wv * 32;

    for (int win = 0; win < 8; win++) {
        const int s0 = win * 512;
        __syncthreads();
#pragma unroll
        for (int it = 0; it < 2; it++) {             // B: 512 rows x 32 bf16
            int idx = it * 1024 + tid;
            *(short8*)&lbB[idx >> 2][(idx & 3) * 8] =
                *(const short8*)(Bb + (size_t)(s0 + (idx >> 2)) * CI_ + (idx & 3) * 8);
        }
#pragma unroll
        for (int it = 0; it < 2; it++) {             // V: 32 rows x 512 bf16
            int idx = it * 1024 + tid;
            *(short8*)&lvV[idx >> 6][(idx & 63) * 8] =
                *(const short8*)(Vb + (size_t)(idx >> 6) * N_ + s0 + (idx & 63) * 8);
        }
        __syncthreads();

        short8 b0 = *(const short8*)&lbB[c0 + lr][lg * 8];
        short8 b1 = *(const short8*)&lbB[c0 + 16 + lr][lg * 8];
        short4v v00 = *(const short4v*)&lvV[lr][c0 + lg * 4];
        short4v v01 = *(const short4v*)&lvV[lr][c0 + 16 + lg * 4];
        short4v v10 = *(const short4v*)&lvV[16 + lr][c0 + lg * 4];
        short4v v11 = *(const short4v*)&lvV[16 + lr][c0 + 16 + lg * 4];
#pragma unroll
        for (int t = 0; t < 4; t++) {
            // swapped operands: lane holds E*log2e [m=lr][n=c0(+16)+4*lg+i]
            float4v e0 = __builtin_amdgcn_mfma_f32_16x16x32_bf16(b0, afrag[t], zero4, 0, 0, 0);
            float4v e1 = __builtin_amdgcn_mfma_f32_16x16x32_bf16(b1, afrag[t], zero4, 0, 0, 0);
            float p0 = __builtin_amdgcn_exp2f(e0[0]), p1 = __builtin_amdgcn_exp2f(e0[1]);
            float p2 = __builtin_amdgcn_exp2f(e0[2]), p3 = __builtin_amdgcn_exp2f(e0[3]);
            float p4 = __builtin_amdgcn_exp2f(e1[0]), p5 = __builtin_amdgcn_exp2f(e1[1]);
            float p6 = __builtin_amdgcn_exp2f(e1[2]), p7 = __builtin_amdgcn_exp2f(e1[3]);
            srun[t] += ((p0 + p1) + (p2 + p3)) + ((p4 + p5) + (p6 + p7));
            short4v pk0, pk1;
            pk0[0] = f2bf(p0); pk0[1] = f2bf(p1); pk0[2] = f2bf(p2); pk0[3] = f2bf(p3);
            pk1[0] = f2bf(p4); pk1[1] = f2bf(p5); pk1[2] = f2bf(p6); pk1[3] = f2bf(p7);
            acc[t][0] = mfma16(v00, pk0, acc[t][0]);
            acc[t][0] = mfma16(v01, pk1, acc[t][0]);
            acc[t][1] = mfma16(v10, pk0, acc[t][1]);
            acc[t][1] = mfma16(v11, pk1, acc[t][1]);
        }
    }

    __syncthreads();                                 // S1: main loop done
    // per-wave sum reduce: lanes sharing lr
#pragma unroll
    for (int t = 0; t < 4; t++) {
        srun[t] += __shfl_xor(srun[t], 16);
        srun[t] += __shfl_xor(srun[t], 32);
    }
    if (lane < 16) {
#pragma unroll
        for (int t = 0; t < 4; t++) sums[wv][t * 16 + lane] = srun[t];
    }
    if (wv < 4) {                                    // seed tree buffers
#pragma unroll
        for (int t = 0; t < 4; t++)
#pragma unroll
            for (int h = 0; h < 2; h++)
                *(float4v*)&buf4[wv][t * 16 + lr][h * 16 + lg * 4] = acc[t][h];
    }
    // fold output weights (disjoint overlay region)
    for (int i = tid; i < C_ * CI_; i += 1024) {
        int co = i >> 5;
        float inv = w_bn[co] * rsqrtf(w_bn[192 + co] + EPS_);
        wf2[0][i] = inv * Ww[i];                     // flat [co][ci]
    }
    if (tid < C_) {
        float inv = w_bn[tid] * rsqrtf(w_bn[192 + tid] + EPS_);
        bf2v[tid] = inv * Wb[tid] + (w_bn[64 + tid] - w_bn[128 + tid] * inv);
    }
    __syncthreads();                                 // S2
    if (wv >= 4 && wv < 8) {
#pragma unroll
        for (int t = 0; t < 4; t++)
#pragma unroll
            for (int h = 0; h < 2; h++) {
                float4v* p = (float4v*)&buf4[wv - 4][t * 16 + lr][h * 16 + lg * 4];
                float4v u = *p;
#pragma unroll
                for (int j = 0; j < 4; j++) u[j] += acc[t][h][j];
                *p = u;
            }
    }
    if (tid < 64) {
        float s = 0.f;
#pragma unroll
        for (int k = 0; k < 16; k++) s += sums[k][tid];
        sumtot[tid] = 1.0f / s;
    }
    __syncthreads();                                 // S3
    if (wv >= 8 && wv < 12) {
#pragma unroll
        for (int t = 0; t < 4; t++)
#pragma unroll
            for (int h = 0; h < 2; h++) {
                float4v* p = (float4v*)&buf4[wv - 8][t * 16 + lr][h * 16 + lg * 4];
                float4v u = *p;
#pragma unroll
                for (int j = 0; j < 4; j++) u[j] += acc[t][h][j];
                *p = u;
            }
    }
    __syncthreads();                                 // S4
    if (wv >= 12) {
#pragma unroll
        for (int t = 0; t < 4; t++)
#pragma unroll
            for (int h = 0; h < 2; h++) {
                float4v* p = (float4v*)&buf4[wv - 12][t * 16 + lr][h * 16 + lg * 4];
                float4v u = *p;
#pragma unroll
                for (int j = 0; j < 4; j++) u[j] += acc[t][h][j];
                *p = u;
            }
    }
    __syncthreads();                                 // S5
    {   // combine 4 buffers + normalize -> buf4[0]
        int m = (tid * 2) >> 5, ci = (tid * 2) & 31;
        float inv = sumtot[m];
#pragma unroll
        for (int q = 0; q < 2; q++) {
            float yv = (buf4[0][m][ci + q] + buf4[1][m][ci + q]
                      + buf4[2][m][ci + q] + buf4[3][m][ci + q]) * inv;
            buf4[0][m][ci + q] = yv;
        }
    }
    __syncthreads();                                 // S6

    // fused output conv + BN + residual: out[co][m] = x[co][m] + sum_ci wf2*y
    const int mloc = tid & 63;
    const int mg   = r0 + mloc;
    float4v yq[8];
#pragma unroll
    for (int q = 0; q < 8; q++) yq[q] = *(const float4v*)&buf4[0][mloc][q * 4];
    const float* xb2 = (side ? x2 : x1) + (size_t)b * C_ * N_;
    float* ob = out + (size_t)side * (B_ * C_ * N_) + (size_t)b * C_ * N_;
#pragma unroll
    for (int k = 0; k < 4; k++) {
        const int co = wv * 4 + k;
        float a2 = bf2v[co];
#pragma unroll
        for (int ci = 0; ci < CI_; ci++) a2 += wf2[co][ci] * yq[ci >> 2][ci & 3];
        ob[(size_t)co * N_ + mg] = xb2[(size_t)co * N_ + mg] + a2;
    }
}

// ---------------------------------------------------------------------------
extern "C" void kernel_launch(void* const* d_in, const int* in_sizes, int n_in,
                              void* d_out, int out_size, void* d_ws, size_t ws_size,
                              hipStream_t stream)
{
    (void)in_sizes; (void)n_in; (void)out_size; (void)ws_size;
    const float* x1   = (const float*)d_in[0];
    const float* x2   = (const float*)d_in[1];
    const float* g_bn = (const float*)d_in[2];
    const float* g_w  = (const float*)d_in[3];
    const float* g_b  = (const float*)d_in[4];
    const float* t_bn = (const float*)d_in[5];
    const float* t_w  = (const float*)d_in[6];
    const float* t_b  = (const float*)d_in[7];
    const float* p_bn = (const float*)d_in[8];
    const float* p_w  = (const float*)d_in[9];
    const float* p_b  = (const float*)d_in[10];
    const float* w_bn = (const float*)d_in[11];
    const float* W_w  = (const float*)d_in[12];
    const float* W_b  = (const float*)d_in[13];
    float* out = (float*)d_out;

    char* ws = (char*)d_ws;
    const size_t MB = 1u << 20;
    short* th_t = (short*)(ws + 0 * MB);             // [B][N][32] bf16 (x log2e)
    short* ph_t = (short*)(ws + 1 * MB);             // [B][N][32] bf16
    short* g1l  = (short*)(ws + 2 * MB);             // [B][32][N] bf16
    short* g2l  = (short*)(ws + 3 * MB);             // [B][32][N] bf16

    proj_kernel<<<dim3(512), dim3(512), 0, stream>>>(
        x1, x2, g_w, g_b, g_bn, t_w, t_b, t_bn, p_w, p_b, p_bn,
        th_t, ph_t, g1l, g2l);

    apply_kernel<<<dim3(512), dim3(1024), 0, stream>>>(
        th_t, ph_t, g1l, g2l, x1, x2, W_w, W_b, w_bn, out);
}